// Round 1
// baseline (403.448 us; speedup 1.0000x reference)
//
#include <hip/hip_runtime.h>
#include <hip/hip_bf16.h>
#include <stdint.h>

// Problem dims (fixed by reference)
#define NB 16384
#define ND 1024
#define NH 2048
#define NE 8
#define NC 3

typedef __attribute__((ext_vector_type(8))) short short8;
typedef __attribute__((ext_vector_type(4))) short short4v;
typedef __attribute__((ext_vector_type(4))) float f32x4;

// fp32 -> bf16 round-to-nearest-even (bit trick, deterministic)
__device__ __forceinline__ unsigned short f2bf(float f) {
  union { float f; unsigned int u; } v; v.f = f;
  unsigned int u = v.u;
  return (unsigned short)((u + 0x7fffu + ((u >> 16) & 1u)) >> 16);
}

// async global->LDS, 16B per lane
__device__ __forceinline__ void glds16(const void* g, void* l) {
  __builtin_amdgcn_global_load_lds(
      (const __attribute__((address_space(1))) void*)g,
      (__attribute__((address_space(3))) void*)l,
      16, 0, 0);
}

// ---------------------------------------------------------------------------
// Kernel 1: router (fp32 logits + argmax), x->bf16 conversion, out=b2 init,
// per-expert counting + within-bucket rank.
// One block (256 thr) per token row.
// ---------------------------------------------------------------------------
__global__ __launch_bounds__(256) void router_kernel(
    const float* __restrict__ x, const float* __restrict__ Wr,
    const float* __restrict__ br, const float* __restrict__ b2,
    unsigned short* __restrict__ xb, int* __restrict__ topics,
    int* __restrict__ rankb, int* __restrict__ counts,
    float* __restrict__ out) {
  int b = blockIdx.x;
  int t = threadIdx.x;
  const float* xr = x + (size_t)b * ND;
  f32x4 xv = *(const f32x4*)(xr + t * 4);

  // bf16 conversion of this row (4 elems/thread)
  short4v xs;
#pragma unroll
  for (int j = 0; j < 4; ++j) xs[j] = (short)f2bf(xv[j]);
  *(short4v*)(xb + (size_t)b * ND + t * 4) = xs;

  // partial router logits
  float p[NE];
#pragma unroll
  for (int e = 0; e < NE; ++e) p[e] = 0.f;
#pragma unroll
  for (int j = 0; j < 4; ++j) {
    const f32x4* wr4 = (const f32x4*)(Wr + (size_t)(t * 4 + j) * NE);
    f32x4 wa = wr4[0];
    f32x4 wb = wr4[1];
    float xj = xv[j];
    p[0] = fmaf(xj, wa[0], p[0]);
    p[1] = fmaf(xj, wa[1], p[1]);
    p[2] = fmaf(xj, wa[2], p[2]);
    p[3] = fmaf(xj, wa[3], p[3]);
    p[4] = fmaf(xj, wb[0], p[4]);
    p[5] = fmaf(xj, wb[1], p[5]);
    p[6] = fmaf(xj, wb[2], p[6]);
    p[7] = fmaf(xj, wb[3], p[7]);
  }
  // wave64 butterfly reduce
#pragma unroll
  for (int e = 0; e < NE; ++e) {
#pragma unroll
    for (int d = 1; d < 64; d <<= 1) p[e] += __shfl_xor(p[e], d);
  }
  __shared__ float red[4][NE];
  if ((t & 63) == 0) {
#pragma unroll
    for (int e = 0; e < NE; ++e) red[t >> 6][e] = p[e];
  }
  __syncthreads();
  if (t == 0) {
    float best = -1e30f;
    int bi = 0;
#pragma unroll
    for (int e = 0; e < NE; ++e) {
      float v = red[0][e] + red[1][e] + red[2][e] + red[3][e] + br[e];
      if (v > best) { best = v; bi = e; }  // strict > : first max wins (numpy)
    }
    topics[b] = bi;
    rankb[b] = atomicAdd(&counts[bi], 1);
    out[b * NC + 0] = b2[bi * NC + 0];
    out[b * NC + 1] = b2[bi * NC + 1];
    out[b * NC + 2] = b2[bi * NC + 2];
  }
}

// ---------------------------------------------------------------------------
// Kernel 2: exclusive scan of 8 counts (single thread — trivial)
// ---------------------------------------------------------------------------
__global__ void scan_kernel(const int* __restrict__ counts,
                            int* __restrict__ offsets) {
  if (threadIdx.x == 0) {
    int s = 0;
    for (int e = 0; e < NE; ++e) { offsets[e] = s; s += counts[e]; }
  }
}

// ---------------------------------------------------------------------------
// Kernel 3: scatter token ids into per-expert buckets
// ---------------------------------------------------------------------------
__global__ __launch_bounds__(256) void scatter_kernel(
    const int* __restrict__ topics, const int* __restrict__ rankb,
    const int* __restrict__ offsets, int* __restrict__ perm) {
  int b = blockIdx.x * 256 + threadIdx.x;
  if (b < NB) perm[offsets[topics[b]] + rankb[b]] = b;
}

// ---------------------------------------------------------------------------
// Kernel 4: W1 [E][D][H] f32  ->  W1T [E][H][D] bf16  (LDS-tiled transpose)
// ---------------------------------------------------------------------------
__global__ __launch_bounds__(256) void w1t_kernel(
    const float* __restrict__ W1, unsigned short* __restrict__ w1t) {
  __shared__ float tile[64][65];
  int bid = blockIdx.x;
  int e = bid >> 9;        // / (16*32)
  int rem = bid & 511;
  int kb = rem >> 5;       // 16 k-tiles of 64
  int hb = rem & 31;       // 32 h-tiles of 64
  int t = threadIdx.x;
  const float* src = W1 + ((size_t)e * ND + kb * 64) * NH + hb * 64;
#pragma unroll
  for (int i = 0; i < 16; ++i) {
    int idx = i * 256 + t;
    int kl = idx >> 6, hl = idx & 63;
    tile[kl][hl] = src[(size_t)kl * NH + hl];
  }
  __syncthreads();
  unsigned short* dst = w1t + ((size_t)e * NH + hb * 64) * ND + kb * 64;
#pragma unroll
  for (int i = 0; i < 16; ++i) {
    int idx = i * 256 + t;
    int hl = idx >> 6, kl = idx & 63;
    dst[(size_t)hl * ND + kl] = f2bf(tile[kl][hl]);
  }
}

// ---------------------------------------------------------------------------
// Kernel 5: fused gathered GEMM + bias/relu + W2 reduction + atomic combine.
// Tile: 128 rows (gathered tokens of one expert) x 128 h-cols, K=1024.
// 256 threads = 4 waves, each wave owns a 64x64 sub-tile (4x4 MFMA frags).
// grid = E * MAXMT(128) * NTILES(16); inactive tiles early-exit.
// ---------------------------------------------------------------------------
__global__ __launch_bounds__(256) void moe_gemm_kernel(
    const unsigned short* __restrict__ xb, const unsigned short* __restrict__ w1t,
    const float* __restrict__ b1, const float* __restrict__ W2,
    const int* __restrict__ perm, const int* __restrict__ counts,
    const int* __restrict__ offsets, float* __restrict__ out) {
  int bid = blockIdx.x;
  int e = bid >> 11;        // / (128*16)
  int rem = bid & 2047;
  int mt = rem >> 4;
  int nt = rem & 15;
  int cnt = counts[e];
  if (mt * 128 >= cnt) return;
  int off = offsets[e];
  int t = threadIdx.x;
  int lane = t & 63;
  int w = t >> 6, wr = w >> 1, wc = w & 1;

  __shared__ int ridx[128];
  __shared__ unsigned short As[128 * 64];  // [row][k] bf16
  __shared__ unsigned short Bs[128 * 64];  // [hcol][k] bf16

  if (t < 128) {
    int m = mt * 128 + t;
    ridx[t] = perm[off + (m < cnt ? m : cnt - 1)];
  }
  __syncthreads();

  // per-thread staging addresses (4 x 16B per buffer)
  const unsigned short* aptr[4];
  const unsigned short* bptr[4];
  char* dstA[4];
  char* dstB[4];
#pragma unroll
  for (int i = 0; i < 4; ++i) {
    int idx = i * 256 + t;
    int r = idx >> 3;
    int kf = (idx & 7) * 8;
    aptr[i] = xb + (size_t)ridx[r] * ND + kf;
    bptr[i] = w1t + ((size_t)(e * NH + nt * 128 + r)) * ND + kf;
    dstA[i] = (char*)As + idx * 16;
    dstB[i] = (char*)Bs + idx * 16;
  }

  f32x4 acc[4][4];
#pragma unroll
  for (int m = 0; m < 4; ++m)
#pragma unroll
    for (int n = 0; n < 4; ++n) acc[m][n] = (f32x4){0.f, 0.f, 0.f, 0.f};

  int arow = (wr * 64 + (lane & 15)) * 64;
  int brow = (wc * 64 + (lane & 15)) * 64;
  int ksub = (lane >> 4) * 8;

  for (int kt = 0; kt < ND; kt += 64) {
#pragma unroll
    for (int i = 0; i < 4; ++i) {
      glds16(aptr[i] + kt, dstA[i]);
      glds16(bptr[i] + kt, dstB[i]);
    }
    __syncthreads();  // drains vmcnt (compiler emits waitcnt before barrier)
#pragma unroll
    for (int kk = 0; kk < 2; ++kk) {
      short8 af[4], bfr[4];
#pragma unroll
      for (int m = 0; m < 4; ++m)
        af[m] = *(const short8*)&As[arow + m * 1024 + kk * 32 + ksub];
#pragma unroll
      for (int n = 0; n < 4; ++n)
        bfr[n] = *(const short8*)&Bs[brow + n * 1024 + kk * 32 + ksub];
#pragma unroll
      for (int m = 0; m < 4; ++m)
#pragma unroll
        for (int n = 0; n < 4; ++n)
          acc[m][n] = __builtin_amdgcn_mfma_f32_16x16x32_bf16(
              af[m], bfr[n], acc[m][n], 0, 0, 0);
    }
    __syncthreads();
  }

  // Epilogue: h = relu(acc + b1); partial out[row][c] = sum_n h * W2[n][c]
  // C/D frag mapping: col = lane&15, row = (lane>>4)*4 + i   [m89/m91]
  int cg = lane & 15;
  int g = lane >> 4;
  float b1v[4];
  float w2v[4][3];
#pragma unroll
  for (int n = 0; n < 4; ++n) {
    int col = nt * 128 + wc * 64 + n * 16 + cg;
    b1v[n] = b1[e * NH + col];
    const float* w2p = W2 + ((size_t)e * NH + col) * NC;
    w2v[n][0] = w2p[0];
    w2v[n][1] = w2p[1];
    w2v[n][2] = w2p[2];
  }
#pragma unroll
  for (int m = 0; m < 4; ++m) {
#pragma unroll
    for (int i = 0; i < 4; ++i) {
      float s0 = 0.f, s1 = 0.f, s2 = 0.f;
#pragma unroll
      for (int n = 0; n < 4; ++n) {
        float h = acc[m][n][i] + b1v[n];
        h = h > 0.f ? h : 0.f;
        s0 = fmaf(h, w2v[n][0], s0);
        s1 = fmaf(h, w2v[n][1], s1);
        s2 = fmaf(h, w2v[n][2], s2);
      }
      // reduce across the 16 cols this wave covers (lanes cg=0..15 share row)
#pragma unroll
      for (int d = 1; d < 16; d <<= 1) {
        s0 += __shfl_xor(s0, d);
        s1 += __shfl_xor(s1, d);
        s2 += __shfl_xor(s2, d);
      }
      if (cg == 0) {
        int rloc = wr * 64 + m * 16 + g * 4 + i;
        if (mt * 128 + rloc < cnt) {
          int tok = ridx[rloc];
          atomicAdd(&out[tok * NC + 0], s0);
          atomicAdd(&out[tok * NC + 1], s1);
          atomicAdd(&out[tok * NC + 2], s2);
        }
      }
    }
  }
}

// ---------------------------------------------------------------------------
// Workspace layout (needs ~67.3 MB):
//   [0,   32MiB)   x_bf16   [16384][1024]
//   [32,  64MiB)   W1T_bf16 [8][2048][1024]
//   [64MiB ...)    topics[16384], rank[16384], perm[16384], counts[8], offs[8]
// ---------------------------------------------------------------------------
extern "C" void kernel_launch(void* const* d_in, const int* in_sizes, int n_in,
                              void* d_out, int out_size, void* d_ws,
                              size_t ws_size, hipStream_t stream) {
  const float* x = (const float*)d_in[0];
  const float* Wr = (const float*)d_in[1];
  const float* br = (const float*)d_in[2];
  const float* W1 = (const float*)d_in[3];
  const float* b1 = (const float*)d_in[4];
  const float* W2 = (const float*)d_in[5];
  const float* b2 = (const float*)d_in[6];
  float* out = (float*)d_out;

  char* ws = (char*)d_ws;
  unsigned short* xb = (unsigned short*)ws;
  unsigned short* w1t = (unsigned short*)(ws + (size_t)33554432);
  char* meta = ws + (size_t)67108864;
  int* topics = (int*)meta;
  int* rankb = topics + NB;
  int* perm = rankb + NB;
  int* counts = perm + NB;
  int* offsets = counts + NE;

  hipMemsetAsync(counts, 0, 2 * NE * sizeof(int), stream);
  router_kernel<<<NB, 256, 0, stream>>>(x, Wr, br, b2, xb, topics, rankb,
                                        counts, out);
  scan_kernel<<<1, 64, 0, stream>>>(counts, offsets);
  scatter_kernel<<<NB / 256, 256, 0, stream>>>(topics, rankb, offsets, perm);
  w1t_kernel<<<NE * 16 * 32, 256, 0, stream>>>(W1, w1t);
  moe_gemm_kernel<<<NE * 128 * 16, 256, 0, stream>>>(xb, w1t, b1, W2, perm,
                                                     counts, offsets, out);
}

// Round 2
// 273.208 us; speedup vs baseline: 1.4767x; 1.4767x over previous
//
#include <hip/hip_runtime.h>
#include <hip/hip_bf16.h>
#include <stdint.h>

// Problem dims (fixed by reference)
#define NB 16384
#define ND 1024
#define NH 2048
#define NE 8
#define NC 3
#define MAXWL 136  // max active (e,mt) tiles: ceil(16384/128)+7

typedef __attribute__((ext_vector_type(8))) short short8;
typedef __attribute__((ext_vector_type(4))) short short4v;
typedef __attribute__((ext_vector_type(4))) float f32x4;

// fp32 -> bf16 round-to-nearest-even
__device__ __forceinline__ unsigned short f2bf(float f) {
  union { float f; unsigned int u; } v; v.f = f;
  unsigned int u = v.u;
  return (unsigned short)((u + 0x7fffu + ((u >> 16) & 1u)) >> 16);
}

// async global->LDS, 16B per lane (LDS dest must be linear in lane order)
__device__ __forceinline__ void glds16(const void* g, void* l) {
  __builtin_amdgcn_global_load_lds(
      (const __attribute__((address_space(1))) void*)g,
      (__attribute__((address_space(3))) void*)l,
      16, 0, 0);
}

// ---------------------------------------------------------------------------
// Kernel 1: router. One wave per row. Fused x->bf16 conversion. Computes
// fp32 logits (must be fp32: bf16 rounding would flip argmax on near-ties)
// and writes topics[b]. NO atomics (round-1 lesson: 16384 same-line atomics
// serialized at L2 = 196us).
// ---------------------------------------------------------------------------
__global__ __launch_bounds__(256) void router_kernel(
    const float* __restrict__ x, const float* __restrict__ Wr,
    const float* __restrict__ br, unsigned short* __restrict__ xb,
    int* __restrict__ topics) {
  int w = threadIdx.x >> 6, lane = threadIdx.x & 63;
  int row = blockIdx.x * 4 + w;
  const float* xr = x + (size_t)row * ND;
  unsigned short* xbr = xb + (size_t)row * ND;
  float p[NE] = {0.f, 0.f, 0.f, 0.f, 0.f, 0.f, 0.f, 0.f};
#pragma unroll
  for (int i = 0; i < 4; ++i) {
    int k0 = i * 256 + lane * 4;
    f32x4 xv = *(const f32x4*)(xr + k0);
    short4v s;
#pragma unroll
    for (int j = 0; j < 4; ++j) s[j] = (short)f2bf(xv[j]);
    *(short4v*)(xbr + k0) = s;  // coalesced 8B/lane
#pragma unroll
    for (int j = 0; j < 4; ++j) {
      const f32x4* wp = (const f32x4*)(Wr + (size_t)(k0 + j) * NE);
      f32x4 wa = wp[0], wb = wp[1];  // 32KB Wr lives in L1
      float xj = xv[j];
      p[0] = fmaf(xj, wa[0], p[0]);
      p[1] = fmaf(xj, wa[1], p[1]);
      p[2] = fmaf(xj, wa[2], p[2]);
      p[3] = fmaf(xj, wa[3], p[3]);
      p[4] = fmaf(xj, wb[0], p[4]);
      p[5] = fmaf(xj, wb[1], p[5]);
      p[6] = fmaf(xj, wb[2], p[6]);
      p[7] = fmaf(xj, wb[3], p[7]);
    }
  }
#pragma unroll
  for (int e = 0; e < NE; ++e) {
#pragma unroll
    for (int d = 1; d < 64; d <<= 1) p[e] += __shfl_xor(p[e], d);
  }
  if (lane == 0) {
    float best = -1e30f;
    int bi = 0;
#pragma unroll
    for (int e = 0; e < NE; ++e) {
      float v = p[e] + br[e];
      if (v > best) { best = v; bi = e; }  // strict > : first max (numpy)
    }
    topics[row] = bi;
  }
}

// ---------------------------------------------------------------------------
// Kernel 2: ranker. ONE block, 1024 threads, 16 rows/thread.
// Packed-u16 Hillis-Steele scan of per-thread 8-expert histograms ->
// stable rank -> perm scatter. Also: counts/offsets, compact worklist of
// active (e,mt) tiles, and coalesced out = b2[topic] init.
// All register arrays are compile-time indexed (rule #20).
// ---------------------------------------------------------------------------
__global__ __launch_bounds__(1024) void ranker_kernel(
    const int* __restrict__ topics, const float* __restrict__ b2,
    int* __restrict__ perm, int* __restrict__ counts,
    int* __restrict__ offsets, int* __restrict__ worklist,
    int* __restrict__ n_wl, float* __restrict__ out) {
  int tid = threadIdx.x;
  __shared__ uint4 sbuf[1024];
  __shared__ int soff[NE];

  int t[16];
  const int4* tp = (const int4*)(topics + tid * 16);
#pragma unroll
  for (int i = 0; i < 4; ++i) {
    int4 v = tp[i];
    t[i * 4 + 0] = v.x; t[i * 4 + 1] = v.y;
    t[i * 4 + 2] = v.z; t[i * 4 + 3] = v.w;
  }
  int h[NE] = {0, 0, 0, 0, 0, 0, 0, 0};
#pragma unroll
  for (int i = 0; i < 16; ++i) {
#pragma unroll
    for (int q = 0; q < NE; ++q) h[q] += (t[i] == q);
  }
  // pack 8 counters into 4 u32 (16-bit fields; totals <= 16384 < 65536)
  uint4 pk;
  pk.x = (unsigned)h[0] | ((unsigned)h[1] << 16);
  pk.y = (unsigned)h[2] | ((unsigned)h[3] << 16);
  pk.z = (unsigned)h[4] | ((unsigned)h[5] << 16);
  pk.w = (unsigned)h[6] | ((unsigned)h[7] << 16);
  uint4 own = pk;
  sbuf[tid] = pk;
  __syncthreads();
  for (int d = 1; d < 1024; d <<= 1) {
    uint4 v = {0u, 0u, 0u, 0u};
    if (tid >= d) v = sbuf[tid - d];
    __syncthreads();
    pk.x += v.x; pk.y += v.y; pk.z += v.z; pk.w += v.w;
    sbuf[tid] = pk;
    __syncthreads();
  }
  if (tid == 0) {
    uint4 tot = sbuf[1023];
    int c[NE] = {(int)(tot.x & 0xffff), (int)(tot.x >> 16),
                 (int)(tot.y & 0xffff), (int)(tot.y >> 16),
                 (int)(tot.z & 0xffff), (int)(tot.z >> 16),
                 (int)(tot.w & 0xffff), (int)(tot.w >> 16)};
    int s = 0, nw = 0;
    for (int e = 0; e < NE; ++e) {
      counts[e] = c[e];
      offsets[e] = s;
      soff[e] = s;
      s += c[e];
      for (int mt = 0; mt * 128 < c[e]; ++mt) worklist[nw++] = (e << 16) | mt;
    }
    *n_wl = nw;
  }
  __syncthreads();
  // exclusive prefix (fieldwise; no cross-field borrow since values < 65536)
  uint4 ex;
  ex.x = pk.x - own.x; ex.y = pk.y - own.y;
  ex.z = pk.z - own.z; ex.w = pk.w - own.w;
  int r[NE] = {soff[0] + (int)(ex.x & 0xffff), soff[1] + (int)(ex.x >> 16),
               soff[2] + (int)(ex.y & 0xffff), soff[3] + (int)(ex.y >> 16),
               soff[4] + (int)(ex.z & 0xffff), soff[5] + (int)(ex.z >> 16),
               soff[6] + (int)(ex.w & 0xffff), soff[7] + (int)(ex.w >> 16)};
#pragma unroll
  for (int i = 0; i < 16; ++i) {
    int e = t[i];
    int pos = 0;
#pragma unroll
    for (int q = 0; q < NE; ++q) pos = (e == q) ? r[q] : pos;
    perm[pos] = tid * 16 + i;
#pragma unroll
    for (int q = 0; q < NE; ++q) r[q] += (e == q);
  }
  // out = b2[topic] init, coalesced (12B/row, consecutive rows across lanes)
  __syncthreads();
  for (int row = tid; row < NB; row += 1024) {
    int e = topics[row];  // L2-hot
    out[row * NC + 0] = b2[e * NC + 0];
    out[row * NC + 1] = b2[e * NC + 1];
    out[row * NC + 2] = b2[e * NC + 2];
  }
}

// ---------------------------------------------------------------------------
// Kernel 3: W1 [E][D][H] f32 -> W1T [E][H][D] bf16, LDS-tiled, vectorized
// both sides (f32x4 global reads, short4 global writes).
// ---------------------------------------------------------------------------
__global__ __launch_bounds__(256) void w1t_kernel(
    const float* __restrict__ W1, unsigned short* __restrict__ w1t) {
  __shared__ float tile[64][65];
  int bid = blockIdx.x;
  int e = bid >> 9;
  int rem = bid & 511;
  int kb = rem >> 5;
  int hb = rem & 31;
  int t = threadIdx.x;
  const float* src = W1 + ((size_t)e * ND + kb * 64) * NH + hb * 64;
#pragma unroll
  for (int i = 0; i < 4; ++i) {
    int idx = i * 256 + t;
    int kl = idx >> 4;
    int h0 = (idx & 15) * 4;
    f32x4 v = *(const f32x4*)(src + (size_t)kl * NH + h0);
    tile[kl][h0 + 0] = v[0];
    tile[kl][h0 + 1] = v[1];
    tile[kl][h0 + 2] = v[2];
    tile[kl][h0 + 3] = v[3];
  }
  __syncthreads();
  unsigned short* dst = w1t + ((size_t)e * NH + hb * 64) * ND + kb * 64;
#pragma unroll
  for (int i = 0; i < 4; ++i) {
    int idx = i * 256 + t;
    int hl = idx >> 4;
    int kq = (idx & 15) * 4;
    short4v s;
#pragma unroll
    for (int j = 0; j < 4; ++j) s[j] = (short)f2bf(tile[kq + j][hl]);
    *(short4v*)(dst + (size_t)hl * ND + kq) = s;  // 8B/lane coalesced
  }
}

// ---------------------------------------------------------------------------
// Kernel 4: fused gathered GEMM + bias/relu + W2 reduce + atomic combine.
// 128x128 tile, BK=64, 4 waves x (4x4) 16x16x32 bf16 MFMA frags.
// Worklist-driven grid (all blocks active). LDS chunk XOR-swizzle
// (m173 pattern: pre-swizzled global source + swizzled ds_read; LDS dest
// stays linear for global_load_lds).
// ---------------------------------------------------------------------------
__global__ __launch_bounds__(256) void moe_gemm_kernel(
    const unsigned short* __restrict__ xb, const unsigned short* __restrict__ w1t,
    const float* __restrict__ b1, const float* __restrict__ W2,
    const int* __restrict__ perm, const int* __restrict__ counts,
    const int* __restrict__ offsets, const int* __restrict__ worklist,
    const int* __restrict__ n_wl, float* __restrict__ out) {
  int nt = blockIdx.x & 15;
  int wi = blockIdx.x >> 4;
  if (wi >= *n_wl) return;
  int item = worklist[wi];
  int e = item >> 16;
  int mt = item & 0xffff;
  int cnt = counts[e];
  int off = offsets[e];
  int t = threadIdx.x;
  int lane = t & 63;
  int w = t >> 6, wr = w >> 1, wc = w & 1;

  __shared__ int ridx[128];
  __shared__ unsigned short As[128 * 64];  // slot(r,c) holds global chunk c^(r&7)
  __shared__ unsigned short Bs[128 * 64];

  if (t < 128) {
    int m = mt * 128 + t;
    ridx[t] = perm[off + (m < cnt ? m : cnt - 1)];
  }
  __syncthreads();

  // staging addresses: 16B chunk c of row r sourced from global chunk c^(r&7)
  const unsigned short* aptr[4];
  const unsigned short* bptr[4];
  char* dstA[4];
  char* dstB[4];
#pragma unroll
  for (int i = 0; i < 4; ++i) {
    int idx = i * 256 + t;
    int r = idx >> 3;
    int c = idx & 7;
    int cs = c ^ (r & 7);
    aptr[i] = xb + (size_t)ridx[r] * ND + cs * 8;
    bptr[i] = w1t + ((size_t)(e * NH + nt * 128 + r)) * ND + cs * 8;
    dstA[i] = (char*)As + idx * 16;
    dstB[i] = (char*)Bs + idx * 16;
  }

  // hoist epilogue weights above K-loop (hide L2 latency under MFMA)
  int cg = lane & 15;
  int g = lane >> 4;
  float b1v[4];
  float w2v[4][3];
#pragma unroll
  for (int n = 0; n < 4; ++n) {
    int col = nt * 128 + wc * 64 + n * 16 + cg;
    b1v[n] = b1[e * NH + col];
    const float* w2p = W2 + ((size_t)e * NH + col) * NC;
    w2v[n][0] = w2p[0];
    w2v[n][1] = w2p[1];
    w2v[n][2] = w2p[2];
  }

  f32x4 acc[4][4];
#pragma unroll
  for (int m = 0; m < 4; ++m)
#pragma unroll
    for (int n = 0; n < 4; ++n) acc[m][n] = (f32x4){0.f, 0.f, 0.f, 0.f};

  int arow = (wr * 64 + (lane & 15)) * 64;
  int brow = (wc * 64 + (lane & 15)) * 64;
  int sx = lane & 7;  // row&7 for all this lane's fragment rows

  for (int kt = 0; kt < ND; kt += 64) {
#pragma unroll
    for (int i = 0; i < 4; ++i) {
      glds16(aptr[i] + kt, dstA[i]);
      glds16(bptr[i] + kt, dstB[i]);
    }
    __syncthreads();
#pragma unroll
    for (int kk = 0; kk < 2; ++kk) {
      int ch = ((kk * 4 + g) ^ sx) * 8;  // swizzled chunk for logical k-chunk
      short8 af[4], bfr[4];
#pragma unroll
      for (int m = 0; m < 4; ++m)
        af[m] = *(const short8*)&As[arow + m * 1024 + ch];
#pragma unroll
      for (int n = 0; n < 4; ++n)
        bfr[n] = *(const short8*)&Bs[brow + n * 1024 + ch];
#pragma unroll
      for (int m = 0; m < 4; ++m)
#pragma unroll
        for (int n = 0; n < 4; ++n)
          acc[m][n] = __builtin_amdgcn_mfma_f32_16x16x32_bf16(
              af[m], bfr[n], acc[m][n], 0, 0, 0);
    }
    __syncthreads();
  }

  // Epilogue: h = relu(acc + b1); out[row][c] += sum_h h * W2[h][c]
  // C/D frag mapping: col = lane&15, row = (lane>>4)*4 + i   [m89/m91]
#pragma unroll
  for (int m = 0; m < 4; ++m) {
#pragma unroll
    for (int i = 0; i < 4; ++i) {
      float s0 = 0.f, s1 = 0.f, s2 = 0.f;
#pragma unroll
      for (int n = 0; n < 4; ++n) {
        float h = acc[m][n][i] + b1v[n];
        h = h > 0.f ? h : 0.f;
        s0 = fmaf(h, w2v[n][0], s0);
        s1 = fmaf(h, w2v[n][1], s1);
        s2 = fmaf(h, w2v[n][2], s2);
      }
#pragma unroll
      for (int d = 1; d < 16; d <<= 1) {
        s0 += __shfl_xor(s0, d);
        s1 += __shfl_xor(s1, d);
        s2 += __shfl_xor(s2, d);
      }
      if (cg == 0) {
        int rloc = wr * 64 + m * 16 + g * 4 + i;
        if (mt * 128 + rloc < cnt) {
          int tok = ridx[rloc];
          atomicAdd(&out[tok * NC + 0], s0);
          atomicAdd(&out[tok * NC + 1], s1);
          atomicAdd(&out[tok * NC + 2], s2);
        }
      }
    }
  }
}

// ---------------------------------------------------------------------------
// Workspace layout (~64.2 MB):
//   [0,   32MiB)   x_bf16   [16384][1024]
//   [32,  64MiB)   W1T_bf16 [8][2048][1024]
//   [64MiB ...)    topics[16384], perm[16384], counts[8], offsets[8],
//                  worklist[256], n_wl
// ---------------------------------------------------------------------------
extern "C" void kernel_launch(void* const* d_in, const int* in_sizes, int n_in,
                              void* d_out, int out_size, void* d_ws,
                              size_t ws_size, hipStream_t stream) {
  const float* x = (const float*)d_in[0];
  const float* Wr = (const float*)d_in[1];
  const float* br = (const float*)d_in[2];
  const float* W1 = (const float*)d_in[3];
  const float* b1 = (const float*)d_in[4];
  const float* W2 = (const float*)d_in[5];
  const float* b2 = (const float*)d_in[6];
  float* out = (float*)d_out;

  char* ws = (char*)d_ws;
  unsigned short* xb = (unsigned short*)ws;
  unsigned short* w1t = (unsigned short*)(ws + (size_t)33554432);
  int* topics = (int*)(ws + (size_t)67108864);
  int* perm = topics + NB;
  int* counts = perm + NB;
  int* offsets = counts + NE;
  int* worklist = offsets + NE;
  int* n_wl = worklist + 256;

  router_kernel<<<NB / 4, 256, 0, stream>>>(x, Wr, br, xb, topics);
  ranker_kernel<<<1, 1024, 0, stream>>>(topics, b2, perm, counts, offsets,
                                        worklist, n_wl, out);
  w1t_kernel<<<NE * 16 * 32, 256, 0, stream>>>(W1, w1t);
  moe_gemm_kernel<<<MAXWL * 16, 256, 0, stream>>>(xb, w1t, b1, W2, perm,
                                                  counts, offsets, worklist,
                                                  n_wl, out);
}